// Round 9
// baseline (251.338 us; speedup 1.0000x reference)
//
#include <hip/hip_runtime.h>
#include <stdint.h>

// Exact fp32 reproduction of the numpy reference requires no FMA contraction
// and identical association order everywhere below.
#pragma clang fp contract(off)

#define B_    4
#define NV_   6890
#define NF_   27552     // 2*13776
#define IMG_  128
#define UV_   256
#define NPIX  (IMG_*IMG_)

#define TS_     8                 // tile edge in pixels
#define TPB_    (IMG_/TS_)        // 16 tiles per row/col
#define NTILE_  (TPB_*TPB_)       // 256 tiles per batch
#define NBIN_   (B_*TPB_*TPB_)    // 1024 bins
#define NBKT_   16                // depth buckets per bin (by face zmin)
#define NCH_    4                 // chunk-blocks per bin (tail parallelism)
#define LIST_CAP 1572864          // entries (6 MB each list); need ~1.2M

// ---------------------------------------------------------------- projection
// Also reduces the exact per-batch z-range (z > 0 always, so uint-bit
// ordering of the float is monotone).
__global__ void __launch_bounds__(256) project_k(
    const float* __restrict__ cam, const float* __restrict__ verts,
    float* __restrict__ vp, unsigned* __restrict__ zmn,
    unsigned* __restrict__ zmx) {
  __shared__ unsigned smn[B_], smx[B_];
  int idx = blockIdx.x * 256 + threadIdx.x;
  if (threadIdx.x < B_) { smn[threadIdx.x] = 0xFFFFFFFFu; smx[threadIdx.x] = 0u; }
  __syncthreads();
  if (idx < B_ * NV_) {
    int b = idx / NV_;
    float c0 = cam[b * 3 + 0], c1 = cam[b * 3 + 1], c2 = cam[b * 3 + 2];
    float tz = 500.0f / (64.0f * c0);                // FLENGTH/(p*cam0), p=64
    const float* src = verts + (size_t)idx * 3;
    float* dst = vp + (size_t)idx * 3;
    dst[0] = c0 * (src[0] + c1);
    dst[1] = c0 * (src[1] + c2);
    float z = src[2] + tz;
    dst[2] = z;
    atomicMin(&smn[b], __float_as_uint(z));
    atomicMax(&smx[b], __float_as_uint(z));
  }
  __syncthreads();
  if (threadIdx.x < B_) {
    atomicMin(&zmn[threadIdx.x], smn[threadIdx.x]);
    atomicMax(&zmx[threadIdx.x], smx[threadIdx.x]);
  }
}

// ------------------------------------------------------------------- binning
// Backface cull (area_c < -1e-3, bit-safe bound proven in R1) + bbox(+-1px)
// -> range of overlapped 8x8 tiles (+-1 px margin: accepted pixels exceed the
// fp bbox by <~1e-3 px only). On accept also returns zminF = min(z0,z1,z2):
// zp = 1/(b0/z0+b1/z1+b2/z2) >= zminF rigorously (all z>0, b>=0, sum=1).
__device__ __forceinline__ int face_tiles(
    const float* __restrict__ vp, const int* __restrict__ faces, int b, int f,
    int& tx0, int& tx1, int& ty0, int& ty1, float& zminF) {
  int ia = faces[f * 3 + 0], ib = faces[f * 3 + 1], ic = faces[f * 3 + 2];
  const float* vb = vp + (size_t)b * NV_ * 3;
  float x0 = vb[ia * 3 + 0], y0 = vb[ia * 3 + 1];
  float x1 = vb[ib * 3 + 0], y1 = vb[ib * 3 + 1];
  float x2 = vb[ic * 3 + 0], y2 = vb[ic * 3 + 1];
  float area_c = (x1 - x0) * (y2 - y0) - (y1 - y0) * (x2 - x0);
  if (area_c < -1e-3f) return 0;
  float xmn = fminf(x0, fminf(x1, x2)), xmx = fmaxf(x0, fmaxf(x1, x2));
  float ymn = fminf(y0, fminf(y1, y2)), ymx = fmaxf(y0, fmaxf(y1, y2));
  int jlo = (int)floorf((xmn + 1.0f) * 64.0f - 0.5f) - 1;
  int jhi = (int)ceilf ((xmx + 1.0f) * 64.0f - 0.5f) + 1;
  int ilo = (int)floorf((1.0f - ymx) * 64.0f - 0.5f) - 1;
  int ihi = (int)ceilf ((1.0f - ymn) * 64.0f - 0.5f) + 1;
  if (jhi < 0 || ihi < 0 || jlo > IMG_ - 1 || ilo > IMG_ - 1) return 0;
  jlo = max(jlo, 0); ilo = max(ilo, 0);
  jhi = min(jhi, IMG_ - 1); ihi = min(ihi, IMG_ - 1);
  tx0 = jlo >> 3; tx1 = jhi >> 3; ty0 = ilo >> 3; ty1 = ihi >> 3;
  float z0 = vb[ia * 3 + 2], z1 = vb[ib * 3 + 2], z2 = vb[ic * 3 + 2];
  zminF = fminf(z0, fminf(z1, z2));
  return 1;
}

// R5-validated block-local LDS count aggregation at BIN level (~12 us).
// Also caches packed rect + depth bucket q per (b,f) for the fill pass.
__global__ void __launch_bounds__(256) bin_count_k(
    const float* __restrict__ vp, const int* __restrict__ faces,
    const unsigned* __restrict__ zmn, const unsigned* __restrict__ zmx,
    int* __restrict__ cnt, int* __restrict__ rects) {
  __shared__ int scnt[NTILE_];
  int f = blockIdx.x * 256 + threadIdx.x;
  int b = blockIdx.y;
  scnt[threadIdx.x] = 0;
  __syncthreads();
  int tx0, tx1, ty0, ty1; float zf;
  int valid =
      (f < NF_) ? face_tiles(vp, faces, b, f, tx0, tx1, ty0, ty1, zf) : 0;
  int q = 0;
  if (valid) {
    float zlo = __uint_as_float(zmn[b]);
    float zhi = __uint_as_float(zmx[b]);
    float sc = 16.0f / (zhi - zlo);
    q = (int)((zf - zlo) * sc);
    q = min(NBKT_ - 1, max(0, q));
  }
  if (f < NF_)
    rects[(size_t)b * NF_ + f] =
        valid ? (tx0 | (tx1 << 4) | (ty0 << 8) | (ty1 << 12) | (1 << 16) |
                 (q << 17))
              : 0;
  if (valid)
    for (int ty = ty0; ty <= ty1; ++ty)
      for (int tx = tx0; tx <= tx1; ++tx)
        atomicAdd(&scnt[ty * TPB_ + tx], 1);
  __syncthreads();
  int t = threadIdx.x;
  int v = scnt[t];
  if (v > 0) atomicAdd(&cnt[b * NTILE_ + t], v);
}

// Exclusive scan over the 1024 per-bin counts -> off (segment base) and cur
// (fill cursor).
__global__ void __launch_bounds__(1024) scan_k(
    const int* __restrict__ cnt, int* __restrict__ off, int* __restrict__ cur) {
  __shared__ int sm[NBIN_];
  int t = threadIdx.x;
  int v = cnt[t];
  sm[t] = v;
  __syncthreads();
  for (int d = 1; d < NBIN_; d <<= 1) {
    int u = (t >= d) ? sm[t - d] : 0;
    __syncthreads();
    sm[t] += u;
    __syncthreads();
  }
  int o = sm[t] - v;
  off[t] = o;
  cur[t] = o;
}

// R5-validated block-local fill: stage 1 LDS counts, one global reservation
// atomic per (block, bin), stage 2 rank + write. Bin segments contiguous ->
// coalesced bursts. Entries pack fid | (q<<16); within-bin order irrelevant
// (the (zp,fid) lexicographic min is order-free).
__global__ void __launch_bounds__(256) bin_fill_k(
    const int* __restrict__ rects, int* __restrict__ cur,
    int* __restrict__ list1) {
  __shared__ int scnt[NTILE_];
  __shared__ int sbase[NTILE_];
  int f = blockIdx.x * 256 + threadIdx.x;
  int b = blockIdx.y;
  scnt[threadIdx.x] = 0;
  __syncthreads();
  int rv = (f < NF_) ? rects[(size_t)b * NF_ + f] : 0;
  int valid = (rv >> 16) & 1;
  int tx0 = rv & 15, tx1 = (rv >> 4) & 15;
  int ty0 = (rv >> 8) & 15, ty1 = (rv >> 12) & 15;
  int q = (rv >> 17) & 15;
  if (valid)
    for (int ty = ty0; ty <= ty1; ++ty)
      for (int tx = tx0; tx <= tx1; ++tx)
        atomicAdd(&scnt[ty * TPB_ + tx], 1);
  __syncthreads();
  int t = threadIdx.x;
  int v = scnt[t];
  if (v > 0) sbase[t] = atomicAdd(&cur[b * NTILE_ + t], v);
  __syncthreads();
  scnt[t] = 0;            // reuse as per-bin rank counter
  __syncthreads();
  if (valid) {
    for (int ty = ty0; ty <= ty1; ++ty)
      for (int tx = tx0; tx <= tx1; ++tx) {
        int bin = ty * TPB_ + tx;
        int r = atomicAdd(&scnt[bin], 1);
        int slot = sbase[bin] + r;
        if (slot < LIST_CAP) list1[slot] = f | (q << 16);
      }
  }
}

// Per-bin counting sort by depth bucket: one block per bin. Pass 1 LDS
// histogram of q (coalesced reads), serial 16-scan -> absolute cell offsets
// (offq/cntq for the raster), pass 2 scatter fid into bucket-ordered list2.
// No cell-level global atomics anywhere.
__global__ void __launch_bounds__(256) sort_k(
    const int* __restrict__ cnt, const int* __restrict__ off,
    const int* __restrict__ list1, int* __restrict__ list2,
    int* __restrict__ offq, int* __restrict__ cntq) {
  __shared__ int h[NBKT_], hc[NBKT_];
  int bin = blockIdx.x;
  int n = cnt[bin];
  int base = off[bin];
  int t = threadIdx.x;
  if (t < NBKT_) h[t] = 0;
  __syncthreads();
  for (int i = t; i < n; i += 256)
    atomicAdd(&h[(list1[base + i] >> 16) & 15], 1);
  __syncthreads();
  if (t == 0) {
    int s = 0;
    for (int k = 0; k < NBKT_; ++k) {
      int v = h[k];
      h[k] = s;
      hc[k] = s;
      offq[bin * NBKT_ + k] = base + s;
      cntq[bin * NBKT_ + k] = v;
      s += v;
    }
  }
  __syncthreads();
  for (int i = t; i < n; i += 256) {
    int e = list1[base + i];
    int q = (e >> 16) & 15;
    int r = atomicAdd(&hc[q], 1);
    list2[base + r] = e & 0xFFFF;
  }
}

// ---------------------------------------------------------------- rasterizer
// NCH_ chunk-blocks per bin (grid.y): chunk c processes batches s=c, c+NCH_,
// ... of each bucket, front-to-back, with its OWN persistent per-pixel
// partial min (LDS pmin). R9: this parallelizes the silhouette-bin tail that
// made R8 latency-bound (one serial block per bin, VALUBusy 14%).
//
// EARLY EXIT on the PARTIAL min is bit-safe: pmin entries are actual achieved
// face depths, so partial_z < edge(q) - 1e-3 implies every face in buckets
// >= q (zp >= zminF >= edge - ~5e-6 mapping slop) is strictly worse than a
// key already in this block's merge contribution -> the global (zp,fid) min
// over all blocks is unchanged (R7/R8-validated logic, margin 200x slop).
// Inside test `area>0 && !(min3(w)<0)` == reference post-divide b>=0
// (R3-R8 validated, absmax 0.0). Approximate-depth gate (R6, margin 1.001)
// runs the exact 7-divide reference chain only for potential improvements.
// Merge: one atomicMin per pixel per block (R4/R5-validated pattern).
__global__ void __launch_bounds__(256) raster_k(
    const float* __restrict__ vp, const int* __restrict__ faces,
    const int* __restrict__ list2, const int* __restrict__ cntq,
    const int* __restrict__ offq, const unsigned* __restrict__ zmn,
    const unsigned* __restrict__ zmx, unsigned long long* __restrict__ zkey) {
  __shared__ float4 fd[4][5][64];   // per-wave staging (wave-private)
  __shared__ unsigned long long pmin[64];
  __shared__ unsigned long long mg[4][64];
  int bin = blockIdx.x;
  int ch = blockIdx.y;
  int b = bin >> 8;
  int t = bin & 255;
  int tyT = t >> 4, txT = t & 15;
  int ws = threadIdx.x >> 6, lane = threadIdx.x & 63;
  int pi = tyT * TS_ + (lane >> 3);
  int pj = txT * TS_ + (lane & 7);
  // exact: (2j+1)/128-1 and 1-(2i+1)/128 are multiples of 2^-7 in [-1,1]
  float px = fmaf((float)pj, 0.015625f, -0.9921875f);
  float py = fmaf((float)pi, -0.015625f, 0.9921875f);
  float zlo = __uint_as_float(zmn[b]);
  float bw16 = (__uint_as_float(zmx[b]) - zlo) * 0.0625f;
  if (threadIdx.x < 64) pmin[threadIdx.x] = ~0ull;
  __syncthreads();

  for (int q = 0; q < NBKT_; ++q) {
    unsigned long long kb = pmin[lane];
    if (q > 0) {
      // block-uniform exit test on the block's partial min
      unsigned kz = (unsigned)(kb >> 32);
      for (int d = 1; d < 64; d <<= 1) {
        unsigned o = (unsigned)__shfl_xor((int)kz, d, 64);
        kz = kz > o ? kz : o;
      }
      if (kz != 0xFFFFFFFFu) {
        float edge = fmaf((float)q, bw16, zlo);
        if (__uint_as_float(kz) < edge - 1e-3f) break;
      }
    }
    int cell = (bin << 4) + q;
    int nq = cntq[cell];
    if (nq == 0) continue;
    int base = offq[cell];
    float gate = __uint_as_float((unsigned)(kb >> 32)) * 1.001f;  // NaN if empty

    int nbat = (nq + 255) >> 8;
    for (int s = ch; s < nbat; s += NCH_) {
      int seg = (s << 8) + (ws << 6);
      int mw = min(nq - seg, 64);
      if (mw > 0) {
        if (lane < mw) {
          int fid = list2[base + seg + lane];
          int ia = faces[fid * 3 + 0], ib = faces[fid * 3 + 1],
              ic = faces[fid * 3 + 2];
          const float* vb = vp + (size_t)b * NV_ * 3;
          float X0 = vb[ia * 3 + 0], Y0 = vb[ia * 3 + 1], Z0 = vb[ia * 3 + 2];
          float X1 = vb[ib * 3 + 0], Y1 = vb[ib * 3 + 1], Z1 = vb[ib * 3 + 2];
          float X2 = vb[ic * 3 + 0], Y2 = vb[ic * 3 + 1], Z2 = vb[ic * 3 + 2];
          fd[ws][0][lane] = make_float4(X2 - X1, Y2 - Y1, X1, Y1);   // d21, v1
          fd[ws][1][lane] = make_float4(X0 - X2, Y0 - Y2, X2, Y2);   // d02, v2
          fd[ws][2][lane] = make_float4(X1 - X0, Y1 - Y0, X0, Y0);   // d10, v0
          fd[ws][3][lane] = make_float4(Z0, Z1, Z2, __int_as_float(fid));
          fd[ws][4][lane] =
              make_float4(Z1 * Z2, Z0 * Z2, Z0 * Z1, Z0 * Z1 * Z2);
        }
        // fd[ws] is wave-private: no block barrier needed (compiler inserts
        // the intra-wave lgkmcnt waits).
        for (int k = 0; k < mw; ++k) {
          float4 A = fd[ws][0][k];
          float4 Bv = fd[ws][1][k];
          float4 Cv = fd[ws][2][k];
          float w0 = A.x * (py - A.w) - A.y * (px - A.z);
          float w1 = Bv.x * (py - Bv.w) - Bv.y * (px - Bv.z);
          float w2 = Cv.x * (py - Cv.w) - Cv.y * (px - Cv.z);
          float area = (w0 + w1) + w2;
          float mn = fminf(w0, fminf(w1, w2));
          if (area > 0.0f && !(mn < 0.0f)) {
            float4 P = fd[ws][4][k];
            float num = (w0 * P.x + w1 * P.y) + w2 * P.z;  // approx: any order
            float zpa = (area * P.w) * __builtin_amdgcn_rcpf(num);
            if (!(zpa > gate)) {                           // NaN-safe gate
              float4 Z = fd[ws][3][k];
              float b0 = w0 / area, b1 = w1 / area, b2 = w2 / area;
              float invz = (b0 / Z.x + b1 / Z.y) + b2 / Z.z;
              float zp = 1.0f / (invz == 0.0f ? 1.0f : invz);
              if (zp > 0.1f && zp < 25.0f) {
                unsigned long long key =
                    ((unsigned long long)__float_as_uint(zp) << 32) |
                    (unsigned int)__float_as_int(Z.w);
                if (key < kb) {
                  kb = key;
                  gate = __uint_as_float((unsigned)(kb >> 32)) * 1.001f;
                }
              }
            }
          }
        }
      }
    }
    // merge the 4 waves' bucket results into the persistent per-pixel min
    mg[ws][lane] = kb;
    __syncthreads();
    if (ws == 0) {
      unsigned long long k0 = mg[0][lane];
      unsigned long long k1 = mg[1][lane];
      unsigned long long k2 = mg[2][lane];
      unsigned long long k3 = mg[3][lane];
      k0 = k1 < k0 ? k1 : k0;
      k2 = k3 < k2 ? k3 : k2;
      k0 = k2 < k0 ? k2 : k0;
      unsigned long long p = pmin[lane];
      pmin[lane] = k0 < p ? k0 : p;
    }
    __syncthreads();
  }
  if (ws == 0) {
    unsigned long long k0 = pmin[lane];
    if (k0 != ~0ull)
      atomicMin(zkey + (size_t)b * NPIX + pi * IMG_ + pj, k0);
  }
}

// ------------------------------------------------------------------- shading
#define TAP(ty, tx, wexpr)                                                   \
  {                                                                          \
    int ty_ = (ty), tx_ = (tx);                                              \
    float w_ = (wexpr);                                                      \
    float valid_ =                                                           \
        (tx_ >= 0 && tx_ < UV_ && ty_ >= 0 && ty_ < UV_) ? 1.0f : 0.0f;      \
    float wv_ = w_ * valid_;                                                 \
    int cy_ = min(max(ty_, 0), UV_ - 1), cx_ = min(max(tx_, 0), UV_ - 1);    \
    int o_ = cy_ * UV_ + cx_;                                                \
    cr = cr + img[o_] * wv_;                                                 \
    cg = cg + img[UV_ * UV_ + o_] * wv_;                                     \
    cb = cb + img[2 * UV_ * UV_ + o_] * wv_;                                 \
  }

__global__ void __launch_bounds__(256) shade_k(
    const float* __restrict__ vp, const int* __restrict__ faces,
    const float* __restrict__ uv, const float* __restrict__ samp,
    const unsigned long long* __restrict__ zkey, float* __restrict__ out) {
  int idx = blockIdx.x * 256 + threadIdx.x;
  if (idx >= B_ * NPIX) return;
  int b = idx / NPIX;
  int p = idx - b * NPIX;
  int ii = p / IMG_;
  int jj = p - ii * IMG_;

  unsigned long long key = zkey[idx];
  float cr = 0.0f, cg = 0.0f, cb = 0.0f;
  if (key != 0xFFFFFFFFFFFFFFFFull) {
    int f = (int)(key & 0xFFFFFFFFull);
    int ia = faces[f * 3 + 0], ib = faces[f * 3 + 1], ic = faces[f * 3 + 2];
    const float* vb = vp + (size_t)b * NV_ * 3;
    float x0 = vb[ia * 3 + 0], y0 = vb[ia * 3 + 1];
    float x1 = vb[ib * 3 + 0], y1 = vb[ib * 3 + 1];
    float x2 = vb[ic * 3 + 0], y2 = vb[ic * 3 + 1];
    float px = (float)(2 * jj + 1) / 128.0f - 1.0f;
    float py = 1.0f - (float)(2 * ii + 1) / 128.0f;
    float w0 = (x2 - x1) * (py - y1) - (y2 - y1) * (px - x1);
    float w1 = (x0 - x2) * (py - y2) - (y0 - y2) * (px - x2);
    float w2 = (x1 - x0) * (py - y0) - (y1 - y0) * (px - x0);
    float area = (w0 + w1) + w2;
    float s = (area == 0.0f) ? 1.0f : area;
    float b0 = w0 / s, b1 = w1 / s;
    int t0 = min(max((int)floorf(b0 * 3.0f), 0), 2);
    int t1 = min(max((int)floorf(b1 * 3.0f), 0), 2);

    // lazy texture fetch: textures[b,f,t0,t1,*,c] == bilinear(uv_imgs[b],
    // sampler[f, t0*3+t1]); lighting multiplier is exactly 1.0 -> skipped.
    const float* g = samp + ((size_t)f * 9 + (size_t)(t0 * 3 + t1)) * 2;
    float gx = g[0], gy = g[1];
    float x = (gx + 1.0f) * 128.0f - 0.5f;   // (g+1)*(W*0.5)-0.5, W=256
    float y = (gy + 1.0f) * 128.0f - 0.5f;
    float x0f = floorf(x), y0f = floorf(y);
    float wx = x - x0f, wy = y - y0f;
    int xi = (int)x0f, yi = (int)y0f;
    float omwx = 1.0f - wx, omwy = 1.0f - wy;
    const float* img = uv + (size_t)b * 3 * UV_ * UV_;
    // reference accumulation order: (y0,x0)+(y0,x0+1)+(y0+1,x0)+(y0+1,x0+1)
    TAP(yi,     xi,     omwx * omwy)
    TAP(yi,     xi + 1, wx * omwy)
    TAP(yi + 1, xi,     omwx * wy)
    TAP(yi + 1, xi + 1, wx * wy)
  }
  out[((size_t)b * 3 + 0) * NPIX + p] = cr;
  out[((size_t)b * 3 + 1) * NPIX + p] = cg;
  out[((size_t)b * 3 + 2) * NPIX + p] = cb;
}

// ------------------------------------------------------------------- launch
extern "C" void kernel_launch(void* const* d_in, const int* in_sizes, int n_in,
                              void* d_out, int out_size, void* d_ws,
                              size_t ws_size, hipStream_t stream) {
  const float* cam   = (const float*)d_in[0];
  const float* verts = (const float*)d_in[1];
  const float* uv    = (const float*)d_in[2];
  const float* samp  = (const float*)d_in[3];
  const int*   faces = (const int*)d_in[4];

  char* ws = (char*)d_ws;
  size_t o = 0;
  unsigned long long* zkey = (unsigned long long*)(ws + o);
  o += (size_t)B_ * NPIX * 8;                                   // 512 KB
  float* vp = (float*)(ws + o);
  o += ((size_t)B_ * NV_ * 3 * 4 + 1023) & ~1023ull;            // ~331 KB
  int* cnt  = (int*)(ws + o); o += NBIN_ * 4;
  int* off  = (int*)(ws + o); o += NBIN_ * 4;
  int* cur  = (int*)(ws + o); o += NBIN_ * 4;
  int* offq = (int*)(ws + o); o += NBIN_ * NBKT_ * 4;           // 64 KB
  int* cntq = (int*)(ws + o); o += NBIN_ * NBKT_ * 4;           // 64 KB
  unsigned* zmn = (unsigned*)(ws + o); o += 512;
  unsigned* zmx = (unsigned*)(ws + o); o += 512;
  int* rects = (int*)(ws + o); o += ((size_t)B_ * NF_ * 4 + 1023) & ~1023ull;
  int* list1 = (int*)(ws + o); o += (size_t)LIST_CAP * 4;       // 6 MB
  int* list2 = (int*)(ws + o);                                  // 6 MB

  hipMemsetAsync(zkey, 0xFF, (size_t)B_ * NPIX * 8, stream);
  hipMemsetAsync(cnt, 0, NBIN_ * 4, stream);
  hipMemsetAsync(zmn, 0xFF, B_ * 4, stream);
  hipMemsetAsync(zmx, 0x00, B_ * 4, stream);
  project_k<<<(B_ * NV_ + 255) / 256, 256, 0, stream>>>(cam, verts, vp, zmn,
                                                        zmx);
  dim3 bgrid((NF_ + 255) / 256, B_);
  bin_count_k<<<bgrid, 256, 0, stream>>>(vp, faces, zmn, zmx, cnt, rects);
  scan_k<<<1, NBIN_, 0, stream>>>(cnt, off, cur);
  bin_fill_k<<<bgrid, 256, 0, stream>>>(rects, cur, list1);
  sort_k<<<NBIN_, 256, 0, stream>>>(cnt, off, list1, list2, offq, cntq);
  raster_k<<<dim3(NBIN_, NCH_), 256, 0, stream>>>(vp, faces, list2, cntq, offq,
                                                  zmn, zmx, zkey);
  shade_k<<<(B_ * NPIX + 255) / 256, 256, 0, stream>>>(vp, faces, uv, samp,
                                                       zkey, (float*)d_out);
}

// Round 10
// 243.644 us; speedup vs baseline: 1.0316x; 1.0316x over previous
//
#include <hip/hip_runtime.h>
#include <stdint.h>

// Exact fp32 reproduction of the numpy reference requires no FMA contraction
// and identical association order everywhere below.
#pragma clang fp contract(off)

#define B_    4
#define NV_   6890
#define NF_   27552     // 2*13776
#define IMG_  128
#define UV_   256
#define NPIX  (IMG_*IMG_)

#define TS_     8                 // tile edge in pixels
#define TPB_    (IMG_/TS_)        // 16 tiles per row/col
#define NTILE_  (TPB_*TPB_)       // 256 tiles per batch
#define NBIN_   (B_*TPB_*TPB_)    // 1024 bins
#define NBKT_   16                // depth buckets per bin (by face zmin)
#define LIST_CAP 1572864          // entries (6 MB each list); need ~1.2M
#define ITEMS_MAX 40960           // >= LIST_CAP/64/... hard bound on items

// --------------------------------------------------------------------- init
// Replaces 4 hipMemsetAsync dispatches: cnt=0, zmn=inf-bits, zmx=0,
// zdone=0xFFFFFFFF (NaN bits == "no published depth yet").
__global__ void __launch_bounds__(1024) init_k(
    int* __restrict__ cnt, unsigned* __restrict__ zmn,
    unsigned* __restrict__ zmx, unsigned* __restrict__ zdone) {
  int t = threadIdx.x;
  cnt[t] = 0;
  zdone[t] = 0xFFFFFFFFu;
  if (t < B_) { zmn[t] = 0xFFFFFFFFu; zmx[t] = 0u; }
}

// ---------------------------------------------------------------- projection
// Also reduces the exact per-batch z-range (z > 0 always, so uint-bit
// ordering of the float is monotone) and initializes zkey to ~0 (fused).
__global__ void __launch_bounds__(256) project_k(
    const float* __restrict__ cam, const float* __restrict__ verts,
    float* __restrict__ vp, unsigned* __restrict__ zmn,
    unsigned* __restrict__ zmx, unsigned long long* __restrict__ zkey) {
  __shared__ unsigned smn[B_], smx[B_];
  int idx = blockIdx.x * 256 + threadIdx.x;
  int nthreads = gridDim.x * 256;
  for (int i = idx; i < B_ * NPIX; i += nthreads) zkey[i] = ~0ull;
  if (threadIdx.x < B_) { smn[threadIdx.x] = 0xFFFFFFFFu; smx[threadIdx.x] = 0u; }
  __syncthreads();
  if (idx < B_ * NV_) {
    int b = idx / NV_;
    float c0 = cam[b * 3 + 0], c1 = cam[b * 3 + 1], c2 = cam[b * 3 + 2];
    float tz = 500.0f / (64.0f * c0);                // FLENGTH/(p*cam0), p=64
    const float* src = verts + (size_t)idx * 3;
    float* dst = vp + (size_t)idx * 3;
    dst[0] = c0 * (src[0] + c1);
    dst[1] = c0 * (src[1] + c2);
    float z = src[2] + tz;
    dst[2] = z;
    atomicMin(&smn[b], __float_as_uint(z));
    atomicMax(&smx[b], __float_as_uint(z));
  }
  __syncthreads();
  if (threadIdx.x < B_) {
    atomicMin(&zmn[threadIdx.x], smn[threadIdx.x]);
    atomicMax(&zmx[threadIdx.x], smx[threadIdx.x]);
  }
}

// ------------------------------------------------------------------- binning
// Backface cull (area_c < -1e-3, bit-safe bound proven in R1) + bbox(+-1px)
// -> range of overlapped 8x8 tiles (+-1 px margin: accepted pixels exceed the
// fp bbox by <~1e-3 px only). On accept also returns zminF = min(z0,z1,z2):
// zp = 1/(b0/z0+b1/z1+b2/z2) >= zminF rigorously (all z>0, b>=0, sum=1).
__device__ __forceinline__ int face_tiles(
    const float* __restrict__ vp, const int* __restrict__ faces, int b, int f,
    int& tx0, int& tx1, int& ty0, int& ty1, float& zminF) {
  int ia = faces[f * 3 + 0], ib = faces[f * 3 + 1], ic = faces[f * 3 + 2];
  const float* vb = vp + (size_t)b * NV_ * 3;
  float x0 = vb[ia * 3 + 0], y0 = vb[ia * 3 + 1];
  float x1 = vb[ib * 3 + 0], y1 = vb[ib * 3 + 1];
  float x2 = vb[ic * 3 + 0], y2 = vb[ic * 3 + 1];
  float area_c = (x1 - x0) * (y2 - y0) - (y1 - y0) * (x2 - x0);
  if (area_c < -1e-3f) return 0;
  float xmn = fminf(x0, fminf(x1, x2)), xmx = fmaxf(x0, fmaxf(x1, x2));
  float ymn = fminf(y0, fminf(y1, y2)), ymx = fmaxf(y0, fmaxf(y1, y2));
  int jlo = (int)floorf((xmn + 1.0f) * 64.0f - 0.5f) - 1;
  int jhi = (int)ceilf ((xmx + 1.0f) * 64.0f - 0.5f) + 1;
  int ilo = (int)floorf((1.0f - ymx) * 64.0f - 0.5f) - 1;
  int ihi = (int)ceilf ((1.0f - ymn) * 64.0f - 0.5f) + 1;
  if (jhi < 0 || ihi < 0 || jlo > IMG_ - 1 || ilo > IMG_ - 1) return 0;
  jlo = max(jlo, 0); ilo = max(ilo, 0);
  jhi = min(jhi, IMG_ - 1); ihi = min(ihi, IMG_ - 1);
  tx0 = jlo >> 3; tx1 = jhi >> 3; ty0 = ilo >> 3; ty1 = ihi >> 3;
  float z0 = vb[ia * 3 + 2], z1 = vb[ib * 3 + 2], z2 = vb[ic * 3 + 2];
  zminF = fminf(z0, fminf(z1, z2));
  return 1;
}

// R5-validated block-local LDS count aggregation at BIN level.
// Also caches packed rect + depth bucket q per (b,f) for the fill pass.
__global__ void __launch_bounds__(256) bin_count_k(
    const float* __restrict__ vp, const int* __restrict__ faces,
    const unsigned* __restrict__ zmn, const unsigned* __restrict__ zmx,
    int* __restrict__ cnt, int* __restrict__ rects) {
  __shared__ int scnt[NTILE_];
  int f = blockIdx.x * 256 + threadIdx.x;
  int b = blockIdx.y;
  scnt[threadIdx.x] = 0;
  __syncthreads();
  int tx0, tx1, ty0, ty1; float zf;
  int valid =
      (f < NF_) ? face_tiles(vp, faces, b, f, tx0, tx1, ty0, ty1, zf) : 0;
  int q = 0;
  if (valid) {
    float zlo = __uint_as_float(zmn[b]);
    float zhi = __uint_as_float(zmx[b]);
    float sc = 16.0f / (zhi - zlo);
    q = (int)((zf - zlo) * sc);
    q = min(NBKT_ - 1, max(0, q));
  }
  if (f < NF_)
    rects[(size_t)b * NF_ + f] =
        valid ? (tx0 | (tx1 << 4) | (ty0 << 8) | (ty1 << 12) | (1 << 16) |
                 (q << 17))
              : 0;
  if (valid)
    for (int ty = ty0; ty <= ty1; ++ty)
      for (int tx = tx0; tx <= tx1; ++tx)
        atomicAdd(&scnt[ty * TPB_ + tx], 1);
  __syncthreads();
  int t = threadIdx.x;
  int v = scnt[t];
  if (v > 0) atomicAdd(&cnt[b * NTILE_ + t], v);
}

// Exclusive scan over the 1024 per-bin counts -> off (segment base) and cur
// (fill cursor).
__global__ void __launch_bounds__(1024) scan_k(
    const int* __restrict__ cnt, int* __restrict__ off, int* __restrict__ cur) {
  __shared__ int sm[NBIN_];
  int t = threadIdx.x;
  int v = cnt[t];
  sm[t] = v;
  __syncthreads();
  for (int d = 1; d < NBIN_; d <<= 1) {
    int u = (t >= d) ? sm[t - d] : 0;
    __syncthreads();
    sm[t] += u;
    __syncthreads();
  }
  int o = sm[t] - v;
  off[t] = o;
  cur[t] = o;
}

// R5-validated block-local fill: stage 1 LDS counts, one global reservation
// atomic per (block, bin), stage 2 rank + write. Bin segments contiguous ->
// coalesced bursts. Entries pack fid | (q<<16); within-bin order irrelevant
// (the (zp,fid) lexicographic min is order-free).
__global__ void __launch_bounds__(256) bin_fill_k(
    const int* __restrict__ rects, int* __restrict__ cur,
    int* __restrict__ list1) {
  __shared__ int scnt[NTILE_];
  __shared__ int sbase[NTILE_];
  int f = blockIdx.x * 256 + threadIdx.x;
  int b = blockIdx.y;
  scnt[threadIdx.x] = 0;
  __syncthreads();
  int rv = (f < NF_) ? rects[(size_t)b * NF_ + f] : 0;
  int valid = (rv >> 16) & 1;
  int tx0 = rv & 15, tx1 = (rv >> 4) & 15;
  int ty0 = (rv >> 8) & 15, ty1 = (rv >> 12) & 15;
  int q = (rv >> 17) & 15;
  if (valid)
    for (int ty = ty0; ty <= ty1; ++ty)
      for (int tx = tx0; tx <= tx1; ++tx)
        atomicAdd(&scnt[ty * TPB_ + tx], 1);
  __syncthreads();
  int t = threadIdx.x;
  int v = scnt[t];
  if (v > 0) sbase[t] = atomicAdd(&cur[b * NTILE_ + t], v);
  __syncthreads();
  scnt[t] = 0;            // reuse as per-bin rank counter
  __syncthreads();
  if (valid) {
    for (int ty = ty0; ty <= ty1; ++ty)
      for (int tx = tx0; tx <= tx1; ++tx) {
        int bin = ty * TPB_ + tx;
        int r = atomicAdd(&scnt[bin], 1);
        int slot = sbase[bin] + r;
        if (slot < LIST_CAP) list1[slot] = f | (q << 16);
      }
  }
}

// Per-bin counting sort by depth bucket: one block per bin. Pass 1 LDS
// histogram of q (coalesced reads), serial 16-scan -> absolute cell offsets
// (offq/cntq for the raster), pass 2 scatter fid into bucket-ordered list2.
__global__ void __launch_bounds__(256) sort_k(
    const int* __restrict__ cnt, const int* __restrict__ off,
    const int* __restrict__ list1, int* __restrict__ list2,
    int* __restrict__ offq, int* __restrict__ cntq) {
  __shared__ int h[NBKT_], hc[NBKT_];
  int bin = blockIdx.x;
  int n = cnt[bin];
  int base = off[bin];
  int t = threadIdx.x;
  if (t < NBKT_) h[t] = 0;
  __syncthreads();
  for (int i = t; i < n; i += 256)
    atomicAdd(&h[(list1[base + i] >> 16) & 15], 1);
  __syncthreads();
  if (t == 0) {
    int s = 0;
    for (int k = 0; k < NBKT_; ++k) {
      int v = h[k];
      h[k] = s;
      hc[k] = s;
      offq[bin * NBKT_ + k] = base + s;
      cntq[bin * NBKT_ + k] = v;
      s += v;
    }
  }
  __syncthreads();
  for (int i = t; i < n; i += 256) {
    int e = list1[base + i];
    int q = (e >> 16) & 15;
    int r = atomicAdd(&hc[q], 1);
    list2[base + r] = e & 0xFFFF;
  }
}

// Build the BUCKET-MAJOR flat work-item list: for q=0..15, for bin=0..1023,
// one item per 64-entry batch of cell (bin,q). Item = bin | q<<10 | batch<<14.
// Bucket-major order means all bins' front-depth work dispatches first, so
// zdone publishes land before most deep-bucket items start (perf-only hint;
// correctness never depends on dispatch order).
__global__ void __launch_bounds__(1024) scan2_k(
    const int* __restrict__ cntq, int* __restrict__ items,
    int* __restrict__ nItems) {
  __shared__ int sm[NBIN_];
  int t = threadIdx.x;
  int base = 0;
  for (int q = 0; q < NBKT_; ++q) {
    int nit = (cntq[t * NBKT_ + q] + 63) >> 6;
    sm[t] = nit;
    __syncthreads();
    for (int d = 1; d < NBIN_; d <<= 1) {
      int u = (t >= d) ? sm[t - d] : 0;
      __syncthreads();
      sm[t] += u;
      __syncthreads();
    }
    int o = base + sm[t] - nit;
    int tot = sm[NBIN_ - 1];
    for (int j = 0; j < nit; ++j) {
      int s = o + j;
      if (s < ITEMS_MAX) items[s] = t | (q << 10) | (j << 14);
    }
    base += tot;
    __syncthreads();
  }
  if (t == 0) nItems[0] = min(base, ITEMS_MAX);
}

// ---------------------------------------------------------------- rasterizer
// ONE WAVE per work item (bin, bucket q, 64-face batch): perfectly balanced,
// no per-bucket barriers, no serial tail. Lanes <-> the bin's 8x8 pixels;
// per-pixel (zp,fid) min kept in a register; one atomicMin per covered pixel
// at the end (R4/R5-validated merge pattern).
//
// Cross-block skipping via zdone[bin] (uint float-bits, atomicMin):
//  * publish: a wave whose 64 lanes ALL hold real keys publishes
//    max-over-pixels of achieved depth -> every pixel of the tile has an
//    achieved key <= zdone that is (being) atomicMin'd into zkey.
//  * skip: an item for bucket q>0 returns if zdone < edge(q)-1e-3 — every
//    bucket-q face has zp >= zminF >= edge-~5e-6, so it strictly z-loses to
//    an achieved key at EVERY pixel (ties included) -> global (zp,fid)-min
//    unchanged. Stale/unpublished zdone only costs speed, never correctness.
//  * gate seed: gate = min(gate, zdone*1.001) — skipping a face with
//    zpa > gate implies zp > zdone >= an achieved key's z at this pixel.
// Inside test `area>0 && !(min3(w)<0)` == reference post-divide b>=0
// (R3-R9 validated, absmax 0.0). Approximate-depth gate (R6, margin 1.001,
// rel err <= ~2e-5) runs the exact 7-divide reference chain only for
// potential improvements -> winner keys bit-identical to the reference.
__global__ void __launch_bounds__(256) raster_k(
    const float* __restrict__ vp, const int* __restrict__ faces,
    const int* __restrict__ list2, const int* __restrict__ cntq,
    const int* __restrict__ offq, const unsigned* __restrict__ zmn,
    const unsigned* __restrict__ zmx, const int* __restrict__ items,
    const int* __restrict__ nItems, unsigned* __restrict__ zdone,
    unsigned long long* __restrict__ zkey) {
  __shared__ float4 fd[4][5][64];   // per-wave staging (wave-private)
  int ws = threadIdx.x >> 6, lane = threadIdx.x & 63;
  int widx = blockIdx.x * 4 + ws;
  if (widx >= nItems[0]) return;
  int it = items[widx];
  int bin = it & 1023;
  int q = (it >> 10) & 15;
  int s = it >> 14;
  int b = bin >> 8;
  int t = bin & 255;
  int tyT = t >> 4, txT = t & 15;
  int pi = tyT * TS_ + (lane >> 3);
  int pj = txT * TS_ + (lane & 7);
  // exact: (2j+1)/128-1 and 1-(2i+1)/128 are multiples of 2^-7 in [-1,1]
  float px = fmaf((float)pj, 0.015625f, -0.9921875f);
  float py = fmaf((float)pi, -0.015625f, 0.9921875f);
  float zlo = __uint_as_float(zmn[b]);
  float bw16 = (__uint_as_float(zmx[b]) - zlo) * 0.0625f;

  // fresh device-scope read of the published bound (atomic no-op write)
  unsigned zd = 0xFFFFFFFFu;
  if (lane == 0) zd = atomicMin(&zdone[bin], 0xFFFFFFFFu);
  zd = (unsigned)__shfl((int)zd, 0, 64);
  if (q > 0) {
    float edge = fmaf((float)q, bw16, zlo);
    if (__uint_as_float(zd) < edge - 1e-3f) return;   // NaN-safe (zd unset)
  }
  float gate = __uint_as_float(zd) * 1.001f;          // NaN if unset

  int cell = (bin << 4) + q;
  int nq = cntq[cell];
  int seg = s << 6;
  int mw = min(nq - seg, 64);
  if (mw <= 0) return;
  int base = offq[cell] + seg;

  if (lane < mw) {
    int fid = list2[base + lane];
    int ia = faces[fid * 3 + 0], ib = faces[fid * 3 + 1],
        ic = faces[fid * 3 + 2];
    const float* vb = vp + (size_t)b * NV_ * 3;
    float X0 = vb[ia * 3 + 0], Y0 = vb[ia * 3 + 1], Z0 = vb[ia * 3 + 2];
    float X1 = vb[ib * 3 + 0], Y1 = vb[ib * 3 + 1], Z1 = vb[ib * 3 + 2];
    float X2 = vb[ic * 3 + 0], Y2 = vb[ic * 3 + 1], Z2 = vb[ic * 3 + 2];
    fd[ws][0][lane] = make_float4(X2 - X1, Y2 - Y1, X1, Y1);   // d21, v1
    fd[ws][1][lane] = make_float4(X0 - X2, Y0 - Y2, X2, Y2);   // d02, v2
    fd[ws][2][lane] = make_float4(X1 - X0, Y1 - Y0, X0, Y0);   // d10, v0
    fd[ws][3][lane] = make_float4(Z0, Z1, Z2, __int_as_float(fid));
    fd[ws][4][lane] = make_float4(Z1 * Z2, Z0 * Z2, Z0 * Z1, Z0 * Z1 * Z2);
  }
  // fd[ws] is wave-private: no block barrier needed (compiler inserts the
  // intra-wave lgkmcnt waits) — R8/R9-validated.

  unsigned long long kb = ~0ull;
  for (int k = 0; k < mw; ++k) {
    float4 A = fd[ws][0][k];
    float4 Bv = fd[ws][1][k];
    float4 Cv = fd[ws][2][k];
    float w0 = A.x * (py - A.w) - A.y * (px - A.z);
    float w1 = Bv.x * (py - Bv.w) - Bv.y * (px - Bv.z);
    float w2 = Cv.x * (py - Cv.w) - Cv.y * (px - Cv.z);
    float area = (w0 + w1) + w2;
    float mn = fminf(w0, fminf(w1, w2));
    if (area > 0.0f && !(mn < 0.0f)) {
      float4 P = fd[ws][4][k];
      float num = (w0 * P.x + w1 * P.y) + w2 * P.z;   // approx: any order
      float zpa = (area * P.w) * __builtin_amdgcn_rcpf(num);
      if (!(zpa > gate)) {                            // NaN-safe gate
        float4 Z = fd[ws][3][k];
        float b0 = w0 / area, b1 = w1 / area, b2 = w2 / area;
        float invz = (b0 / Z.x + b1 / Z.y) + b2 / Z.z;
        float zp = 1.0f / (invz == 0.0f ? 1.0f : invz);
        if (zp > 0.1f && zp < 25.0f) {
          unsigned long long key =
              ((unsigned long long)__float_as_uint(zp) << 32) |
              (unsigned int)__float_as_int(Z.w);
          if (key < kb) {
            kb = key;
            gate = fminf(gate,
                         __uint_as_float((unsigned)(kb >> 32)) * 1.001f);
          }
        }
      }
    }
  }

  if (kb != ~0ull)
    atomicMin(zkey + (size_t)b * NPIX + pi * IMG_ + pj, kb);

  // publish an upper bound if every pixel of the tile got a real key
  if (__ballot(kb != ~0ull) == ~0ull) {
    unsigned kz = (unsigned)(kb >> 32);
    for (int d = 1; d < 64; d <<= 1) {
      unsigned o = (unsigned)__shfl_xor((int)kz, d, 64);
      kz = kz > o ? kz : o;
    }
    if (lane == 0) atomicMin(&zdone[bin], kz);
  }
}

// ------------------------------------------------------------------- shading
#define TAP(ty, tx, wexpr)                                                   \
  {                                                                          \
    int ty_ = (ty), tx_ = (tx);                                              \
    float w_ = (wexpr);                                                      \
    float valid_ =                                                           \
        (tx_ >= 0 && tx_ < UV_ && ty_ >= 0 && ty_ < UV_) ? 1.0f : 0.0f;      \
    float wv_ = w_ * valid_;                                                 \
    int cy_ = min(max(ty_, 0), UV_ - 1), cx_ = min(max(tx_, 0), UV_ - 1);    \
    int o_ = cy_ * UV_ + cx_;                                                \
    cr = cr + img[o_] * wv_;                                                 \
    cg = cg + img[UV_ * UV_ + o_] * wv_;                                     \
    cb = cb + img[2 * UV_ * UV_ + o_] * wv_;                                 \
  }

__global__ void __launch_bounds__(256) shade_k(
    const float* __restrict__ vp, const int* __restrict__ faces,
    const float* __restrict__ uv, const float* __restrict__ samp,
    const unsigned long long* __restrict__ zkey, float* __restrict__ out) {
  int idx = blockIdx.x * 256 + threadIdx.x;
  if (idx >= B_ * NPIX) return;
  int b = idx / NPIX;
  int p = idx - b * NPIX;
  int ii = p / IMG_;
  int jj = p - ii * IMG_;

  unsigned long long key = zkey[idx];
  float cr = 0.0f, cg = 0.0f, cb = 0.0f;
  if (key != 0xFFFFFFFFFFFFFFFFull) {
    int f = (int)(key & 0xFFFFFFFFull);
    int ia = faces[f * 3 + 0], ib = faces[f * 3 + 1], ic = faces[f * 3 + 2];
    const float* vb = vp + (size_t)b * NV_ * 3;
    float x0 = vb[ia * 3 + 0], y0 = vb[ia * 3 + 1];
    float x1 = vb[ib * 3 + 0], y1 = vb[ib * 3 + 1];
    float x2 = vb[ic * 3 + 0], y2 = vb[ic * 3 + 1];
    float px = (float)(2 * jj + 1) / 128.0f - 1.0f;
    float py = 1.0f - (float)(2 * ii + 1) / 128.0f;
    float w0 = (x2 - x1) * (py - y1) - (y2 - y1) * (px - x1);
    float w1 = (x0 - x2) * (py - y2) - (y0 - y2) * (px - x2);
    float w2 = (x1 - x0) * (py - y0) - (y1 - y0) * (px - x0);
    float area = (w0 + w1) + w2;
    float s = (area == 0.0f) ? 1.0f : area;
    float b0 = w0 / s, b1 = w1 / s;
    int t0 = min(max((int)floorf(b0 * 3.0f), 0), 2);
    int t1 = min(max((int)floorf(b1 * 3.0f), 0), 2);

    // lazy texture fetch: textures[b,f,t0,t1,*,c] == bilinear(uv_imgs[b],
    // sampler[f, t0*3+t1]); lighting multiplier is exactly 1.0 -> skipped.
    const float* g = samp + ((size_t)f * 9 + (size_t)(t0 * 3 + t1)) * 2;
    float gx = g[0], gy = g[1];
    float x = (gx + 1.0f) * 128.0f - 0.5f;   // (g+1)*(W*0.5)-0.5, W=256
    float y = (gy + 1.0f) * 128.0f - 0.5f;
    float x0f = floorf(x), y0f = floorf(y);
    float wx = x - x0f, wy = y - y0f;
    int xi = (int)x0f, yi = (int)y0f;
    float omwx = 1.0f - wx, omwy = 1.0f - wy;
    const float* img = uv + (size_t)b * 3 * UV_ * UV_;
    // reference accumulation order: (y0,x0)+(y0,x0+1)+(y0+1,x0)+(y0+1,x0+1)
    TAP(yi,     xi,     omwx * omwy)
    TAP(yi,     xi + 1, wx * omwy)
    TAP(yi + 1, xi,     omwx * wy)
    TAP(yi + 1, xi + 1, wx * wy)
  }
  out[((size_t)b * 3 + 0) * NPIX + p] = cr;
  out[((size_t)b * 3 + 1) * NPIX + p] = cg;
  out[((size_t)b * 3 + 2) * NPIX + p] = cb;
}

// ------------------------------------------------------------------- launch
extern "C" void kernel_launch(void* const* d_in, const int* in_sizes, int n_in,
                              void* d_out, int out_size, void* d_ws,
                              size_t ws_size, hipStream_t stream) {
  const float* cam   = (const float*)d_in[0];
  const float* verts = (const float*)d_in[1];
  const float* uv    = (const float*)d_in[2];
  const float* samp  = (const float*)d_in[3];
  const int*   faces = (const int*)d_in[4];

  char* ws = (char*)d_ws;
  size_t o = 0;
  unsigned long long* zkey = (unsigned long long*)(ws + o);
  o += (size_t)B_ * NPIX * 8;                                   // 512 KB
  float* vp = (float*)(ws + o);
  o += ((size_t)B_ * NV_ * 3 * 4 + 1023) & ~1023ull;            // ~331 KB
  int* cnt  = (int*)(ws + o); o += NBIN_ * 4;
  int* off  = (int*)(ws + o); o += NBIN_ * 4;
  int* cur  = (int*)(ws + o); o += NBIN_ * 4;
  int* offq = (int*)(ws + o); o += NBIN_ * NBKT_ * 4;           // 64 KB
  int* cntq = (int*)(ws + o); o += NBIN_ * NBKT_ * 4;           // 64 KB
  unsigned* zmn   = (unsigned*)(ws + o); o += 512;
  unsigned* zmx   = (unsigned*)(ws + o); o += 512;
  unsigned* zdone = (unsigned*)(ws + o); o += NBIN_ * 4;        // 4 KB
  int* nItems = (int*)(ws + o); o += 1024;
  int* items  = (int*)(ws + o); o += (size_t)ITEMS_MAX * 4;     // 160 KB
  int* rects  = (int*)(ws + o); o += ((size_t)B_ * NF_ * 4 + 1023) & ~1023ull;
  int* list1  = (int*)(ws + o); o += (size_t)LIST_CAP * 4;      // 6 MB
  int* list2  = (int*)(ws + o);                                 // 6 MB

  init_k<<<1, 1024, 0, stream>>>(cnt, zmn, zmx, zdone);
  project_k<<<(B_ * NV_ + 255) / 256, 256, 0, stream>>>(cam, verts, vp, zmn,
                                                        zmx, zkey);
  dim3 bgrid((NF_ + 255) / 256, B_);
  bin_count_k<<<bgrid, 256, 0, stream>>>(vp, faces, zmn, zmx, cnt, rects);
  scan_k<<<1, NBIN_, 0, stream>>>(cnt, off, cur);
  bin_fill_k<<<bgrid, 256, 0, stream>>>(rects, cur, list1);
  sort_k<<<NBIN_, 256, 0, stream>>>(cnt, off, list1, list2, offq, cntq);
  scan2_k<<<1, NBIN_, 0, stream>>>(cntq, items, nItems);
  raster_k<<<ITEMS_MAX / 4, 256, 0, stream>>>(vp, faces, list2, cntq, offq,
                                              zmn, zmx, items, nItems, zdone,
                                              zkey);
  shade_k<<<(B_ * NPIX + 255) / 256, 256, 0, stream>>>(vp, faces, uv, samp,
                                                       zkey, (float*)d_out);
}

// Round 11
// 216.959 us; speedup vs baseline: 1.1585x; 1.1230x over previous
//
#include <hip/hip_runtime.h>
#include <stdint.h>

// Exact fp32 reproduction of the numpy reference requires no FMA contraction
// and identical association order everywhere below.
#pragma clang fp contract(off)

#define B_    4
#define NV_   6890
#define NF_   27552     // 2*13776
#define IMG_  128
#define UV_   256
#define NPIX  (IMG_*IMG_)

#define TS_     8                 // tile edge in pixels
#define TPB_    (IMG_/TS_)        // 16 tiles per row/col
#define NTILE_  (TPB_*TPB_)       // 256 tiles per batch
#define NBIN_   (B_*TPB_*TPB_)    // 1024 bins
#define NBKT_   16                // depth buckets per bin (by face zmin)
#define NCELL_B (NTILE_*NBKT_)    // 4096 cells per batch
#define LIST_CAP 1572864          // entries (6 MB); need ~1.2M
#define ITEMS_MAX 40960           // hard bound on wave work items

// --------------------------------------------------------------------- init
// cntq=0 (16K cells), zdone=NaN-bits ("no published depth"), zmn/zmx seeds.
__global__ void __launch_bounds__(1024) init_k(
    int* __restrict__ cntq, unsigned* __restrict__ zmn,
    unsigned* __restrict__ zmx, unsigned* __restrict__ zdone) {
  int t = threadIdx.x;
  for (int i = t; i < NBIN_ * NBKT_; i += 1024) cntq[i] = 0;
  zdone[t] = 0xFFFFFFFFu;
  if (t < B_) { zmn[t] = 0xFFFFFFFFu; zmx[t] = 0u; }
}

// ---------------------------------------------------------------- projection
// Also reduces the exact per-batch z-range (z > 0 always, so uint-bit
// ordering of the float is monotone) and initializes zkey to ~0 (fused).
__global__ void __launch_bounds__(256) project_k(
    const float* __restrict__ cam, const float* __restrict__ verts,
    float* __restrict__ vp, unsigned* __restrict__ zmn,
    unsigned* __restrict__ zmx, unsigned long long* __restrict__ zkey) {
  __shared__ unsigned smn[B_], smx[B_];
  int idx = blockIdx.x * 256 + threadIdx.x;
  int nthreads = gridDim.x * 256;
  for (int i = idx; i < B_ * NPIX; i += nthreads) zkey[i] = ~0ull;
  if (threadIdx.x < B_) { smn[threadIdx.x] = 0xFFFFFFFFu; smx[threadIdx.x] = 0u; }
  __syncthreads();
  if (idx < B_ * NV_) {
    int b = idx / NV_;
    float c0 = cam[b * 3 + 0], c1 = cam[b * 3 + 1], c2 = cam[b * 3 + 2];
    float tz = 500.0f / (64.0f * c0);                // FLENGTH/(p*cam0), p=64
    const float* src = verts + (size_t)idx * 3;
    float* dst = vp + (size_t)idx * 3;
    dst[0] = c0 * (src[0] + c1);
    dst[1] = c0 * (src[1] + c2);
    float z = src[2] + tz;
    dst[2] = z;
    atomicMin(&smn[b], __float_as_uint(z));
    atomicMax(&smx[b], __float_as_uint(z));
  }
  __syncthreads();
  if (threadIdx.x < B_) {
    atomicMin(&zmn[threadIdx.x], smn[threadIdx.x]);
    atomicMax(&zmx[threadIdx.x], smx[threadIdx.x]);
  }
}

// ------------------------------------------------------------------- binning
// Backface cull (area_c < -1e-3, bit-safe bound proven in R1) + bbox(+-1px)
// -> range of overlapped 8x8 tiles (+-1 px margin: accepted pixels exceed the
// fp bbox by <~1e-3 px only). On accept also returns zminF = min(z0,z1,z2):
// zp = 1/(b0/z0+b1/z1+b2/z2) >= zminF rigorously (all z>0, b>=0, sum=1).
__device__ __forceinline__ int face_tiles(
    const float* __restrict__ vp, const int* __restrict__ faces, int b, int f,
    int& tx0, int& tx1, int& ty0, int& ty1, float& zminF) {
  int ia = faces[f * 3 + 0], ib = faces[f * 3 + 1], ic = faces[f * 3 + 2];
  const float* vb = vp + (size_t)b * NV_ * 3;
  float x0 = vb[ia * 3 + 0], y0 = vb[ia * 3 + 1];
  float x1 = vb[ib * 3 + 0], y1 = vb[ib * 3 + 1];
  float x2 = vb[ic * 3 + 0], y2 = vb[ic * 3 + 1];
  float area_c = (x1 - x0) * (y2 - y0) - (y1 - y0) * (x2 - x0);
  if (area_c < -1e-3f) return 0;
  float xmn = fminf(x0, fminf(x1, x2)), xmx = fmaxf(x0, fmaxf(x1, x2));
  float ymn = fminf(y0, fminf(y1, y2)), ymx = fmaxf(y0, fmaxf(y1, y2));
  int jlo = (int)floorf((xmn + 1.0f) * 64.0f - 0.5f) - 1;
  int jhi = (int)ceilf ((xmx + 1.0f) * 64.0f - 0.5f) + 1;
  int ilo = (int)floorf((1.0f - ymx) * 64.0f - 0.5f) - 1;
  int ihi = (int)ceilf ((1.0f - ymn) * 64.0f - 0.5f) + 1;
  if (jhi < 0 || ihi < 0 || jlo > IMG_ - 1 || ilo > IMG_ - 1) return 0;
  jlo = max(jlo, 0); ilo = max(ilo, 0);
  jhi = min(jhi, IMG_ - 1); ihi = min(ihi, IMG_ - 1);
  tx0 = jlo >> 3; tx1 = jhi >> 3; ty0 = ilo >> 3; ty1 = ihi >> 3;
  float z0 = vb[ia * 3 + 2], z1 = vb[ib * 3 + 2], z2 = vb[ic * 3 + 2];
  zminF = fminf(z0, fminf(z1, z2));
  return 1;
}

// R5-style block-local LDS aggregation, now at CELL (tile,bucket) level:
// 4096-int LDS histogram; flush is fire-and-forget global adds spread over
// 16K addresses. Caches packed rect + bucket q per (b,f) for the fill pass.
__global__ void __launch_bounds__(256) bin_count_k(
    const float* __restrict__ vp, const int* __restrict__ faces,
    const unsigned* __restrict__ zmn, const unsigned* __restrict__ zmx,
    int* __restrict__ cntq, int* __restrict__ rects) {
  __shared__ int scnt[NCELL_B];
  int f = blockIdx.x * 256 + threadIdx.x;
  int b = blockIdx.y;
  for (int i = threadIdx.x; i < NCELL_B; i += 256) scnt[i] = 0;
  __syncthreads();
  int tx0, tx1, ty0, ty1; float zf;
  int valid =
      (f < NF_) ? face_tiles(vp, faces, b, f, tx0, tx1, ty0, ty1, zf) : 0;
  int q = 0;
  if (valid) {
    float zlo = __uint_as_float(zmn[b]);
    float zhi = __uint_as_float(zmx[b]);
    float sc = 16.0f / (zhi - zlo);
    q = (int)((zf - zlo) * sc);
    q = min(NBKT_ - 1, max(0, q));
  }
  if (f < NF_)
    rects[(size_t)b * NF_ + f] =
        valid ? (tx0 | (tx1 << 4) | (ty0 << 8) | (ty1 << 12) | (1 << 16) |
                 (q << 17))
              : 0;
  if (valid)
    for (int ty = ty0; ty <= ty1; ++ty)
      for (int tx = tx0; tx <= tx1; ++tx)
        atomicAdd(&scnt[(ty * TPB_ + tx) * NBKT_ + q], 1);
  __syncthreads();
  for (int i = threadIdx.x; i < NCELL_B; i += 256) {
    int v = scnt[i];
    if (v > 0) atomicAdd(&cntq[b * NCELL_B + i], v);
  }
}

// Fused scan: ONE single-block kernel replaces scan_k + scan2_k (the R10
// scan2 did 16 sequential 1024-wide Hillis-Steele scans = ~320 barriers).
// Part A: exclusive scan over all 16384 cells (thread t owns bin t's 16
// cells: serial local scan + ONE 1024-wide Hillis-Steele) -> offq/curq.
// Part B: bucket-major item list — wave w handles bucket q=w; lane owns 16
// bins, serial scan + __shfl_up wave scan (2 block barriers total).
// Item = bin | q<<10 | batch<<14. Bucket-major order -> front-depth work
// dispatches first so zdone publishes land early (perf-only hint).
__global__ void __launch_bounds__(1024) scan_all_k(
    const int* __restrict__ cntq, int* __restrict__ offq,
    int* __restrict__ curq, int* __restrict__ items,
    int* __restrict__ nItems) {
  __shared__ int sm[NBIN_];
  __shared__ int qtot[NBKT_];
  int t = threadIdx.x;
  // ---- Part A: cell offsets
  int base = t * NBKT_;
  int loc[NBKT_];
  int tot = 0;
  for (int i = 0; i < NBKT_; ++i) { loc[i] = tot; tot += cntq[base + i]; }
  sm[t] = tot;
  __syncthreads();
  for (int d = 1; d < NBIN_; d <<= 1) {
    int u = (t >= d) ? sm[t - d] : 0;
    __syncthreads();
    sm[t] += u;
    __syncthreads();
  }
  int pre = sm[t] - tot;
  for (int i = 0; i < NBKT_; ++i) {
    int o = pre + loc[i];
    offq[base + i] = o;
    curq[base + i] = o;
  }
  // ---- Part B: items (wave w <-> bucket q=w; lane owns bins l*16..l*16+15)
  int w = t >> 6, lane = t & 63;
  int q = w;
  int nit[16];
  int ltot = 0;
  for (int i = 0; i < 16; ++i) {
    int bin = lane * 16 + i;
    nit[i] = ltot;
    ltot += (cntq[bin * NBKT_ + q] + 63) >> 6;
  }
  int sc = ltot;
  for (int d = 1; d < 64; d <<= 1) {
    int u = __shfl_up(sc, d, 64);
    if (lane >= d) sc += u;
  }
  int lpre = sc - ltot;
  int wtot = __shfl(sc, 63, 64);
  if (lane == 0) qtot[q] = wtot;
  __syncthreads();
  int qbase = 0;
  for (int k = 0; k < q; ++k) qbase += qtot[k];
  int total = 0;
  for (int k = 0; k < NBKT_; ++k) total += qtot[k];
  for (int i = 0; i < 16; ++i) {
    int bin = lane * 16 + i;
    int ni = (cntq[bin * NBKT_ + q] + 63) >> 6;
    int o = qbase + lpre + nit[i];
    for (int j = 0; j < ni; ++j) {
      int s = o + j;
      if (s < ITEMS_MAX) items[s] = bin | (q << 10) | (j << 14);
    }
  }
  if (t == 0) nItems[0] = min(total, ITEMS_MAX);
}

// Direct bucket-segmented fill (sort_k deleted): R5's reserve+rank pattern
// at CELL granularity. Stage 1 LDS cell counts; stage 2 one reservation
// atomic per (block, nonempty cell); stage 3 re-walk rect, LDS rank, write
// list[sbase+r]. Per-(block,cell) slots contiguous -> cache-friendly writes.
// Within-cell order irrelevant: the (zp,fid) lexicographic min is order-free.
__global__ void __launch_bounds__(256) bin_fill_k(
    const int* __restrict__ rects, int* __restrict__ curq,
    int* __restrict__ list) {
  __shared__ int scnt[NCELL_B];
  __shared__ int sbase[NCELL_B];
  int f = blockIdx.x * 256 + threadIdx.x;
  int b = blockIdx.y;
  for (int i = threadIdx.x; i < NCELL_B; i += 256) scnt[i] = 0;
  __syncthreads();
  int rv = (f < NF_) ? rects[(size_t)b * NF_ + f] : 0;
  int valid = (rv >> 16) & 1;
  int tx0 = rv & 15, tx1 = (rv >> 4) & 15;
  int ty0 = (rv >> 8) & 15, ty1 = (rv >> 12) & 15;
  int q = (rv >> 17) & 15;
  if (valid)
    for (int ty = ty0; ty <= ty1; ++ty)
      for (int tx = tx0; tx <= tx1; ++tx)
        atomicAdd(&scnt[(ty * TPB_ + tx) * NBKT_ + q], 1);
  __syncthreads();
  for (int i = threadIdx.x; i < NCELL_B; i += 256) {
    int v = scnt[i];
    if (v > 0) sbase[i] = atomicAdd(&curq[b * NCELL_B + i], v);
  }
  __syncthreads();
  for (int i = threadIdx.x; i < NCELL_B; i += 256) scnt[i] = 0;
  __syncthreads();
  if (valid)
    for (int ty = ty0; ty <= ty1; ++ty)
      for (int tx = tx0; tx <= tx1; ++tx) {
        int c = (ty * TPB_ + tx) * NBKT_ + q;
        int r = atomicAdd(&scnt[c], 1);
        int slot = sbase[c] + r;
        if (slot < LIST_CAP) list[slot] = f;
      }
}

// ---------------------------------------------------------------- rasterizer
// R10-validated (absmax 0.0), unchanged: ONE WAVE per work item (bin, bucket
// q, 64-face batch). Lanes <-> the bin's 8x8 pixels; per-pixel (zp,fid) min
// in a register; one atomicMin per covered pixel at the end.
// Cross-block skipping via zdone[bin] (publish max-over-pixels achieved
// depth when all 64 lanes hold real keys; skip bucket-q items when
// zdone < edge(q)-1e-3 — every bucket-q face has zp >= zminF >= edge-~5e-6,
// strictly z-losing at EVERY pixel -> global (zp,fid)-min unchanged; stale
// zdone only costs speed). Gate seed zdone*1.001; approximate-depth gate
// (R6, rel err <= ~2e-5) runs the exact 7-divide reference chain only for
// potential improvements -> winner keys bit-identical to the reference.
__global__ void __launch_bounds__(256) raster_k(
    const float* __restrict__ vp, const int* __restrict__ faces,
    const int* __restrict__ list, const int* __restrict__ cntq,
    const int* __restrict__ offq, const unsigned* __restrict__ zmn,
    const unsigned* __restrict__ zmx, const int* __restrict__ items,
    const int* __restrict__ nItems, unsigned* __restrict__ zdone,
    unsigned long long* __restrict__ zkey) {
  __shared__ float4 fd[4][5][64];   // per-wave staging (wave-private)
  int ws = threadIdx.x >> 6, lane = threadIdx.x & 63;
  int widx = blockIdx.x * 4 + ws;
  if (widx >= nItems[0]) return;
  int it = items[widx];
  int bin = it & 1023;
  int q = (it >> 10) & 15;
  int s = it >> 14;
  int b = bin >> 8;
  int t = bin & 255;
  int tyT = t >> 4, txT = t & 15;
  int pi = tyT * TS_ + (lane >> 3);
  int pj = txT * TS_ + (lane & 7);
  // exact: (2j+1)/128-1 and 1-(2i+1)/128 are multiples of 2^-7 in [-1,1]
  float px = fmaf((float)pj, 0.015625f, -0.9921875f);
  float py = fmaf((float)pi, -0.015625f, 0.9921875f);
  float zlo = __uint_as_float(zmn[b]);
  float bw16 = (__uint_as_float(zmx[b]) - zlo) * 0.0625f;

  // fresh device-scope read of the published bound (atomic no-op write)
  unsigned zd = 0xFFFFFFFFu;
  if (lane == 0) zd = atomicMin(&zdone[bin], 0xFFFFFFFFu);
  zd = (unsigned)__shfl((int)zd, 0, 64);
  if (q > 0) {
    float edge = fmaf((float)q, bw16, zlo);
    if (__uint_as_float(zd) < edge - 1e-3f) return;   // NaN-safe (zd unset)
  }
  float gate = __uint_as_float(zd) * 1.001f;          // NaN if unset

  int cell = (bin << 4) + q;
  int nq = cntq[cell];
  int seg = s << 6;
  int mw = min(nq - seg, 64);
  if (mw <= 0) return;
  int base = offq[cell] + seg;

  if (lane < mw) {
    int fid = list[base + lane];
    int ia = faces[fid * 3 + 0], ib = faces[fid * 3 + 1],
        ic = faces[fid * 3 + 2];
    const float* vb = vp + (size_t)b * NV_ * 3;
    float X0 = vb[ia * 3 + 0], Y0 = vb[ia * 3 + 1], Z0 = vb[ia * 3 + 2];
    float X1 = vb[ib * 3 + 0], Y1 = vb[ib * 3 + 1], Z1 = vb[ib * 3 + 2];
    float X2 = vb[ic * 3 + 0], Y2 = vb[ic * 3 + 1], Z2 = vb[ic * 3 + 2];
    fd[ws][0][lane] = make_float4(X2 - X1, Y2 - Y1, X1, Y1);   // d21, v1
    fd[ws][1][lane] = make_float4(X0 - X2, Y0 - Y2, X2, Y2);   // d02, v2
    fd[ws][2][lane] = make_float4(X1 - X0, Y1 - Y0, X0, Y0);   // d10, v0
    fd[ws][3][lane] = make_float4(Z0, Z1, Z2, __int_as_float(fid));
    fd[ws][4][lane] = make_float4(Z1 * Z2, Z0 * Z2, Z0 * Z1, Z0 * Z1 * Z2);
  }
  // fd[ws] is wave-private: no block barrier needed (compiler inserts the
  // intra-wave lgkmcnt waits) — R8-R10 validated.

  unsigned long long kb = ~0ull;
  for (int k = 0; k < mw; ++k) {
    float4 A = fd[ws][0][k];
    float4 Bv = fd[ws][1][k];
    float4 Cv = fd[ws][2][k];
    float w0 = A.x * (py - A.w) - A.y * (px - A.z);
    float w1 = Bv.x * (py - Bv.w) - Bv.y * (px - Bv.z);
    float w2 = Cv.x * (py - Cv.w) - Cv.y * (px - Cv.z);
    float area = (w0 + w1) + w2;
    float mn = fminf(w0, fminf(w1, w2));
    if (area > 0.0f && !(mn < 0.0f)) {
      float4 P = fd[ws][4][k];
      float num = (w0 * P.x + w1 * P.y) + w2 * P.z;   // approx: any order
      float zpa = (area * P.w) * __builtin_amdgcn_rcpf(num);
      if (!(zpa > gate)) {                            // NaN-safe gate
        float4 Z = fd[ws][3][k];
        float b0 = w0 / area, b1 = w1 / area, b2 = w2 / area;
        float invz = (b0 / Z.x + b1 / Z.y) + b2 / Z.z;
        float zp = 1.0f / (invz == 0.0f ? 1.0f : invz);
        if (zp > 0.1f && zp < 25.0f) {
          unsigned long long key =
              ((unsigned long long)__float_as_uint(zp) << 32) |
              (unsigned int)__float_as_int(Z.w);
          if (key < kb) {
            kb = key;
            gate = fminf(gate,
                         __uint_as_float((unsigned)(kb >> 32)) * 1.001f);
          }
        }
      }
    }
  }

  if (kb != ~0ull)
    atomicMin(zkey + (size_t)b * NPIX + pi * IMG_ + pj, kb);

  // publish an upper bound if every pixel of the tile got a real key
  if (__ballot(kb != ~0ull) == ~0ull) {
    unsigned kz = (unsigned)(kb >> 32);
    for (int d = 1; d < 64; d <<= 1) {
      unsigned o = (unsigned)__shfl_xor((int)kz, d, 64);
      kz = kz > o ? kz : o;
    }
    if (lane == 0) atomicMin(&zdone[bin], kz);
  }
}

// ------------------------------------------------------------------- shading
#define TAP(ty, tx, wexpr)                                                   \
  {                                                                          \
    int ty_ = (ty), tx_ = (tx);                                              \
    float w_ = (wexpr);                                                      \
    float valid_ =                                                           \
        (tx_ >= 0 && tx_ < UV_ && ty_ >= 0 && ty_ < UV_) ? 1.0f : 0.0f;      \
    float wv_ = w_ * valid_;                                                 \
    int cy_ = min(max(ty_, 0), UV_ - 1), cx_ = min(max(tx_, 0), UV_ - 1);    \
    int o_ = cy_ * UV_ + cx_;                                                \
    cr = cr + img[o_] * wv_;                                                 \
    cg = cg + img[UV_ * UV_ + o_] * wv_;                                     \
    cb = cb + img[2 * UV_ * UV_ + o_] * wv_;                                 \
  }

__global__ void __launch_bounds__(256) shade_k(
    const float* __restrict__ vp, const int* __restrict__ faces,
    const float* __restrict__ uv, const float* __restrict__ samp,
    const unsigned long long* __restrict__ zkey, float* __restrict__ out) {
  int idx = blockIdx.x * 256 + threadIdx.x;
  if (idx >= B_ * NPIX) return;
  int b = idx / NPIX;
  int p = idx - b * NPIX;
  int ii = p / IMG_;
  int jj = p - ii * IMG_;

  unsigned long long key = zkey[idx];
  float cr = 0.0f, cg = 0.0f, cb = 0.0f;
  if (key != 0xFFFFFFFFFFFFFFFFull) {
    int f = (int)(key & 0xFFFFFFFFull);
    int ia = faces[f * 3 + 0], ib = faces[f * 3 + 1], ic = faces[f * 3 + 2];
    const float* vb = vp + (size_t)b * NV_ * 3;
    float x0 = vb[ia * 3 + 0], y0 = vb[ia * 3 + 1];
    float x1 = vb[ib * 3 + 0], y1 = vb[ib * 3 + 1];
    float x2 = vb[ic * 3 + 0], y2 = vb[ic * 3 + 1];
    float px = (float)(2 * jj + 1) / 128.0f - 1.0f;
    float py = 1.0f - (float)(2 * ii + 1) / 128.0f;
    float w0 = (x2 - x1) * (py - y1) - (y2 - y1) * (px - x1);
    float w1 = (x0 - x2) * (py - y2) - (y0 - y2) * (px - x2);
    float w2 = (x1 - x0) * (py - y0) - (y1 - y0) * (px - x0);
    float area = (w0 + w1) + w2;
    float s = (area == 0.0f) ? 1.0f : area;
    float b0 = w0 / s, b1 = w1 / s;
    int t0 = min(max((int)floorf(b0 * 3.0f), 0), 2);
    int t1 = min(max((int)floorf(b1 * 3.0f), 0), 2);

    // lazy texture fetch: textures[b,f,t0,t1,*,c] == bilinear(uv_imgs[b],
    // sampler[f, t0*3+t1]); lighting multiplier is exactly 1.0 -> skipped.
    const float* g = samp + ((size_t)f * 9 + (size_t)(t0 * 3 + t1)) * 2;
    float gx = g[0], gy = g[1];
    float x = (gx + 1.0f) * 128.0f - 0.5f;   // (g+1)*(W*0.5)-0.5, W=256
    float y = (gy + 1.0f) * 128.0f - 0.5f;
    float x0f = floorf(x), y0f = floorf(y);
    float wx = x - x0f, wy = y - y0f;
    int xi = (int)x0f, yi = (int)y0f;
    float omwx = 1.0f - wx, omwy = 1.0f - wy;
    const float* img = uv + (size_t)b * 3 * UV_ * UV_;
    // reference accumulation order: (y0,x0)+(y0,x0+1)+(y0+1,x0)+(y0+1,x0+1)
    TAP(yi,     xi,     omwx * omwy)
    TAP(yi,     xi + 1, wx * omwy)
    TAP(yi + 1, xi,     omwx * wy)
    TAP(yi + 1, xi + 1, wx * wy)
  }
  out[((size_t)b * 3 + 0) * NPIX + p] = cr;
  out[((size_t)b * 3 + 1) * NPIX + p] = cg;
  out[((size_t)b * 3 + 2) * NPIX + p] = cb;
}

// ------------------------------------------------------------------- launch
extern "C" void kernel_launch(void* const* d_in, const int* in_sizes, int n_in,
                              void* d_out, int out_size, void* d_ws,
                              size_t ws_size, hipStream_t stream) {
  const float* cam   = (const float*)d_in[0];
  const float* verts = (const float*)d_in[1];
  const float* uv    = (const float*)d_in[2];
  const float* samp  = (const float*)d_in[3];
  const int*   faces = (const int*)d_in[4];

  char* ws = (char*)d_ws;
  size_t o = 0;
  unsigned long long* zkey = (unsigned long long*)(ws + o);
  o += (size_t)B_ * NPIX * 8;                                   // 512 KB
  float* vp = (float*)(ws + o);
  o += ((size_t)B_ * NV_ * 3 * 4 + 1023) & ~1023ull;            // ~331 KB
  int* offq = (int*)(ws + o); o += NBIN_ * NBKT_ * 4;           // 64 KB
  int* cntq = (int*)(ws + o); o += NBIN_ * NBKT_ * 4;           // 64 KB
  int* curq = (int*)(ws + o); o += NBIN_ * NBKT_ * 4;           // 64 KB
  unsigned* zmn   = (unsigned*)(ws + o); o += 512;
  unsigned* zmx   = (unsigned*)(ws + o); o += 512;
  unsigned* zdone = (unsigned*)(ws + o); o += NBIN_ * 4;        // 4 KB
  int* nItems = (int*)(ws + o); o += 1024;
  int* items  = (int*)(ws + o); o += (size_t)ITEMS_MAX * 4;     // 160 KB
  int* rects  = (int*)(ws + o); o += ((size_t)B_ * NF_ * 4 + 1023) & ~1023ull;
  int* list   = (int*)(ws + o);                                 // 6 MB

  init_k<<<1, 1024, 0, stream>>>(cntq, zmn, zmx, zdone);
  project_k<<<(B_ * NV_ + 255) / 256, 256, 0, stream>>>(cam, verts, vp, zmn,
                                                        zmx, zkey);
  dim3 bgrid((NF_ + 255) / 256, B_);
  bin_count_k<<<bgrid, 256, 0, stream>>>(vp, faces, zmn, zmx, cntq, rects);
  scan_all_k<<<1, 1024, 0, stream>>>(cntq, offq, curq, items, nItems);
  bin_fill_k<<<bgrid, 256, 0, stream>>>(rects, curq, list);
  raster_k<<<ITEMS_MAX / 4, 256, 0, stream>>>(vp, faces, list, cntq, offq,
                                              zmn, zmx, items, nItems, zdone,
                                              zkey);
  shade_k<<<(B_ * NPIX + 255) / 256, 256, 0, stream>>>(vp, faces, uv, samp,
                                                       zkey, (float*)d_out);
}